// Round 1
// baseline (166.419 us; speedup 1.0000x reference)
//
#include <hip/hip_runtime.h>

#define N_GROUPS 4096
#define K_POS 4
#define HID 256
#define M_NEG 256
#define KDIM 768  // (K_POS-1)*HID

// ---------------- Kernel 1: predicts = hist_x @ W^T + b ----------------
// A (M=4096, K=768): row n = emb + n*1024 (768 contiguous floats)
// B (N=256, K=768): W row-major (256 x 768)
// C (4096, 256) fp32 -> ws
__global__ __launch_bounds__(256) void gemm_predicts(
    const float* __restrict__ emb, const float* __restrict__ W,
    const float* __restrict__ bias, float* __restrict__ pred) {
  constexpr int BM = 64, BN = 64, BK = 32;
  __shared__ float As[BK][BM];
  __shared__ float Bs[BK][BN];
  const int bm = blockIdx.x, bn = blockIdx.y;
  const int tid = threadIdx.x;
  const int tx = tid & 15, ty = tid >> 4;
  float acc[4][4] = {};

  for (int k0 = 0; k0 < KDIM; k0 += BK) {
#pragma unroll
    for (int i = 0; i < 2; ++i) {
      const int f = tid + i * 256;          // float4 slot
      const int row = f >> 3;               // 64 rows
      const int kc = (f & 7) << 2;          // 0..28
      const float4 av = *(const float4*)(emb + (size_t)(bm * BM + row) * (K_POS * HID) + k0 + kc);
      As[kc + 0][row] = av.x; As[kc + 1][row] = av.y;
      As[kc + 2][row] = av.z; As[kc + 3][row] = av.w;
      const float4 bv = *(const float4*)(W + (size_t)(bn * BN + row) * KDIM + k0 + kc);
      Bs[kc + 0][row] = bv.x; Bs[kc + 1][row] = bv.y;
      Bs[kc + 2][row] = bv.z; Bs[kc + 3][row] = bv.w;
    }
    __syncthreads();
#pragma unroll
    for (int k = 0; k < BK; ++k) {
      const float4 a = *(const float4*)&As[k][ty << 2];
      const float4 b = *(const float4*)&Bs[k][tx << 2];
      const float aa[4] = {a.x, a.y, a.z, a.w};
      const float bb[4] = {b.x, b.y, b.z, b.w};
#pragma unroll
      for (int i = 0; i < 4; ++i)
#pragma unroll
        for (int j = 0; j < 4; ++j) acc[i][j] += aa[i] * bb[j];
    }
    __syncthreads();
  }

  const int col = bn * BN + (tx << 2);
  const float4 bv = *(const float4*)(bias + col);
  const float bb[4] = {bv.x, bv.y, bv.z, bv.w};
#pragma unroll
  for (int i = 0; i < 4; ++i) {
    const int row = bm * BM + (ty << 2) + i;
    float4 o;
    o.x = acc[i][0] + bb[0]; o.y = acc[i][1] + bb[1];
    o.z = acc[i][2] + bb[2]; o.w = acc[i][3] + bb[3];
    *(float4*)(pred + (size_t)row * HID + col) = o;
  }
}

// ---------------- Kernel 2: per-row logits + logsumexp loss ----------------
// block = row n, 256 threads = 4 waves; wave w owns negatives [w*64, w*64+64)
__global__ __launch_bounds__(256) void loss_rows(
    const float* __restrict__ emb, const float* __restrict__ pred,
    const int* __restrict__ neg_perm, float* __restrict__ row_loss) {
  const int n = blockIdx.x;
  const int tid = threadIdx.x;
  const int lane = tid & 63, wv = tid >> 6;
  __shared__ float red[8];
  __shared__ float posv_s;

  // predicts fragment: lane holds p[lane*4 .. lane*4+3]
  const float4 pv = *(const float4*)(pred + (size_t)n * HID + (lane << 2));

  // positive logit (wave 0)
  if (wv == 0) {
    const float4 hv = *(const float4*)(emb + ((size_t)n * K_POS + (K_POS - 1)) * HID + (lane << 2));
    float s = pv.x * hv.x + pv.y * hv.y + pv.z * hv.z + pv.w * hv.w;
    s += __shfl_xor(s, 1);  s += __shfl_xor(s, 2);  s += __shfl_xor(s, 4);
    s += __shfl_xor(s, 8);  s += __shfl_xor(s, 16); s += __shfl_xor(s, 32);
    if (lane == 0) posv_s = s;
  }

  // negative index for j = wv*64 + lane (one coalesced load per wave)
  const int raw = neg_perm[(size_t)n * M_NEG + tid];
  const int idx = raw + (raw >= n * K_POS ? K_POS : 0);

  float myneg = 0.f;  // lane l will end up holding neg_logit[wv*64 + l]
#pragma unroll 1
  for (int q = 0; q < 64; q += 4) {
    float s[4];
#pragma unroll
    for (int u = 0; u < 4; ++u) {
      const int id = __shfl(idx, q + u);
      const float4 rv = *(const float4*)(emb + (size_t)id * HID + (lane << 2));
      s[u] = pv.x * rv.x + pv.y * rv.y + pv.z * rv.z + pv.w * rv.w;
    }
#pragma unroll
    for (int u = 0; u < 4; ++u) {
      float t = s[u];
      t += __shfl_xor(t, 1);  t += __shfl_xor(t, 2);  t += __shfl_xor(t, 4);
      t += __shfl_xor(t, 8);  t += __shfl_xor(t, 16); t += __shfl_xor(t, 32);
      if (lane == q + u) myneg = t;  // all lanes hold the full sum after butterfly
    }
  }
  __syncthreads();
  const float posv = posv_s;

  // block max over {myneg(256), posv}
  float mx = myneg;
  mx = fmaxf(mx, __shfl_xor(mx, 1));  mx = fmaxf(mx, __shfl_xor(mx, 2));
  mx = fmaxf(mx, __shfl_xor(mx, 4));  mx = fmaxf(mx, __shfl_xor(mx, 8));
  mx = fmaxf(mx, __shfl_xor(mx, 16)); mx = fmaxf(mx, __shfl_xor(mx, 32));
  if (lane == 0) red[wv] = mx;
  __syncthreads();
  float gmx = fmaxf(fmaxf(red[0], red[1]), fmaxf(red[2], red[3]));
  gmx = fmaxf(gmx, posv);

  float se = __expf(myneg - gmx);
  se += __shfl_xor(se, 1);  se += __shfl_xor(se, 2);  se += __shfl_xor(se, 4);
  se += __shfl_xor(se, 8);  se += __shfl_xor(se, 16); se += __shfl_xor(se, 32);
  if (lane == 0) red[4 + wv] = se;
  __syncthreads();

  if (tid == 0) {
    const float tot = red[4] + red[5] + red[6] + red[7] + __expf(posv - gmx);
    row_loss[n] = __logf(tot) + gmx - posv;  // lse - pos_logit
  }
}

// ---------------- Kernel 3: deterministic mean ----------------
__global__ __launch_bounds__(256) void reduce_mean(
    const float* __restrict__ row_loss, float* __restrict__ out) {
  const int tid = threadIdx.x;
  const int lane = tid & 63, wv = tid >> 6;
  float s = 0.f;
  for (int i = tid; i < N_GROUPS; i += 256) s += row_loss[i];
  s += __shfl_xor(s, 1);  s += __shfl_xor(s, 2);  s += __shfl_xor(s, 4);
  s += __shfl_xor(s, 8);  s += __shfl_xor(s, 16); s += __shfl_xor(s, 32);
  __shared__ float red[4];
  if (lane == 0) red[wv] = s;
  __syncthreads();
  if (tid == 0) out[0] = (red[0] + red[1] + red[2] + red[3]) * (1.0f / N_GROUPS);
}

extern "C" void kernel_launch(void* const* d_in, const int* in_sizes, int n_in,
                              void* d_out, int out_size, void* d_ws, size_t ws_size,
                              hipStream_t stream) {
  const float* emb = (const float*)d_in[0];
  const float* W = (const float*)d_in[1];
  const float* b = (const float*)d_in[2];
  const int* neg_perm = (const int*)d_in[4];
  float* out = (float*)d_out;

  float* pred = (float*)d_ws;                        // 4096*256 fp32 = 4 MB
  float* row_loss = pred + (size_t)N_GROUPS * HID;   // 16 KB

  gemm_predicts<<<dim3(N_GROUPS / 64, HID / 64), 256, 0, stream>>>(emb, W, b, pred);
  loss_rows<<<N_GROUPS, 256, 0, stream>>>(emb, pred, neg_perm, row_loss);
  reduce_mean<<<1, 256, 0, stream>>>(row_loss, out);
}

// Round 2
// 122.580 us; speedup vs baseline: 1.3576x; 1.3576x over previous
//
#include <hip/hip_runtime.h>

#define N_GROUPS 4096
#define K_POS 4
#define HID 256
#define M_NEG 256
#define KDIM 768  // (K_POS-1)*HID
#define N_EMB (N_GROUPS * K_POS)

typedef __attribute__((ext_vector_type(8))) short bf16x8;
typedef __attribute__((ext_vector_type(4))) float f32x4;

__device__ inline ushort f2bf(float f) {
  uint x = __float_as_uint(f);
  uint r = (x + 0x7fffu + ((x >> 16) & 1u)) >> 16;
  return (ushort)r;
}
__device__ inline float bf2f(ushort u) {
  return __uint_as_float(((uint)u) << 16);
}

// ---------------- Kernel 0: fp32 -> bf16 for emb and W ----------------
#define N4_EMB (N_EMB * HID / 4)      // 1048576
#define N4_W   (KDIM * HID / 4)       // 49152
__global__ __launch_bounds__(256) void to_bf16(
    const float* __restrict__ emb, const float* __restrict__ W,
    ushort* __restrict__ embB, ushort* __restrict__ WB) {
  const int i = blockIdx.x * 256 + threadIdx.x;
  if (i < N4_EMB) {
    const float4 v = ((const float4*)emb)[i];
    ushort4 o = {f2bf(v.x), f2bf(v.y), f2bf(v.z), f2bf(v.w)};
    ((ushort4*)embB)[i] = o;
  } else if (i < N4_EMB + N4_W) {
    const int j = i - N4_EMB;
    const float4 v = ((const float4*)W)[j];
    ushort4 o = {f2bf(v.x), f2bf(v.y), f2bf(v.z), f2bf(v.w)};
    ((ushort4*)WB)[j] = o;
  }
}

// ---------------- Kernel 1: predicts = hist_x @ W^T + b (MFMA bf16) ----------------
// 4 waves/block; wave computes one 16x16 output tile via 24x mfma_16x16x32.
// A row m = embB flat [m*1024, m*1024+768); B row n = WB[n*768 ...].
// Same k-mapping used for A and B fragments => permutation-invariant.
__global__ __launch_bounds__(256) void gemm_mfma(
    const ushort* __restrict__ embB, const ushort* __restrict__ WB,
    const float* __restrict__ bias, ushort* __restrict__ predB) {
  const int wv = threadIdx.x >> 6;
  const int l = threadIdx.x & 63;
  const int mt = blockIdx.x * 4 + wv;   // 0..255
  const int nt = blockIdx.y;            // 0..15
  const int r = l & 15, g = l >> 4;

  const short* A = (const short*)embB + (size_t)(mt * 16 + r) * (K_POS * HID) + g * 8;
  const short* B = (const short*)WB + (size_t)(nt * 16 + r) * KDIM + g * 8;

  f32x4 acc = {0.f, 0.f, 0.f, 0.f};
#pragma unroll
  for (int k0 = 0; k0 < KDIM; k0 += 32) {
    const bf16x8 a = *(const bf16x8*)(A + k0);
    const bf16x8 b = *(const bf16x8*)(B + k0);
    acc = __builtin_amdgcn_mfma_f32_16x16x32_bf16(a, b, acc, 0, 0, 0);
  }
  // C/D: col = lane&15, row = (lane>>4)*4 + j   [m89-verified]
  const int col = nt * 16 + r;
  const float bb = bias[col];
#pragma unroll
  for (int j = 0; j < 4; ++j) {
    predB[(size_t)(mt * 16 + g * 4 + j) * HID + col] = f2bf(acc[j] + bb);
  }
}

// ---------------- Kernel 2: per-row logits + logsumexp loss (bf16 gather) ----------------
__global__ __launch_bounds__(256) void loss_rows(
    const ushort* __restrict__ embB, const ushort* __restrict__ predB,
    const int* __restrict__ neg_perm, float* __restrict__ row_loss) {
  const int n = blockIdx.x;
  const int tid = threadIdx.x;
  const int lane = tid & 63, wv = tid >> 6;
  __shared__ float red[8];
  __shared__ float posv_s;

  // lane holds pred[n][4*lane .. 4*lane+3]
  const ushort4 pu = *(const ushort4*)(predB + (size_t)n * HID + (lane << 2));
  const float p0 = bf2f(pu.x), p1 = bf2f(pu.y), p2 = bf2f(pu.z), p3 = bf2f(pu.w);

  if (wv == 0) {
    const ushort4 hu = *(const ushort4*)(embB + ((size_t)n * K_POS + (K_POS - 1)) * HID + (lane << 2));
    float s = p0 * bf2f(hu.x) + p1 * bf2f(hu.y) + p2 * bf2f(hu.z) + p3 * bf2f(hu.w);
    s += __shfl_xor(s, 1);  s += __shfl_xor(s, 2);  s += __shfl_xor(s, 4);
    s += __shfl_xor(s, 8);  s += __shfl_xor(s, 16); s += __shfl_xor(s, 32);
    if (lane == 0) posv_s = s;
  }

  const int raw = neg_perm[(size_t)n * M_NEG + tid];
  const int idx = raw + (raw >= n * K_POS ? K_POS : 0);

  float myneg = 0.f;  // lane l ends up holding neg_logit[wv*64 + l]
#pragma unroll 1
  for (int q = 0; q < 64; q += 8) {
    float s[8];
#pragma unroll
    for (int u = 0; u < 8; ++u) {
      const int id = __shfl(idx, q + u);
      const ushort4 ev = *(const ushort4*)(embB + (size_t)id * HID + (lane << 2));
      s[u] = p0 * bf2f(ev.x) + p1 * bf2f(ev.y) + p2 * bf2f(ev.z) + p3 * bf2f(ev.w);
    }
#pragma unroll
    for (int u = 0; u < 8; ++u) {
      float t = s[u];
      t += __shfl_xor(t, 1);  t += __shfl_xor(t, 2);  t += __shfl_xor(t, 4);
      t += __shfl_xor(t, 8);  t += __shfl_xor(t, 16); t += __shfl_xor(t, 32);
      if (lane == q + u) myneg = t;
    }
  }
  __syncthreads();
  const float posv = posv_s;

  float mx = myneg;
  mx = fmaxf(mx, __shfl_xor(mx, 1));  mx = fmaxf(mx, __shfl_xor(mx, 2));
  mx = fmaxf(mx, __shfl_xor(mx, 4));  mx = fmaxf(mx, __shfl_xor(mx, 8));
  mx = fmaxf(mx, __shfl_xor(mx, 16)); mx = fmaxf(mx, __shfl_xor(mx, 32));
  if (lane == 0) red[wv] = mx;
  __syncthreads();
  float gmx = fmaxf(fmaxf(red[0], red[1]), fmaxf(red[2], red[3]));
  gmx = fmaxf(gmx, posv);

  float se = __expf(myneg - gmx);
  se += __shfl_xor(se, 1);  se += __shfl_xor(se, 2);  se += __shfl_xor(se, 4);
  se += __shfl_xor(se, 8);  se += __shfl_xor(se, 16); se += __shfl_xor(se, 32);
  if (lane == 0) red[4 + wv] = se;
  __syncthreads();

  if (tid == 0) {
    const float tot = red[4] + red[5] + red[6] + red[7] + __expf(posv - gmx);
    row_loss[n] = __logf(tot) + gmx - posv;
  }
}

// ---------------- Kernel 3: deterministic mean ----------------
__global__ __launch_bounds__(256) void reduce_mean(
    const float* __restrict__ row_loss, float* __restrict__ out) {
  const int tid = threadIdx.x;
  const int lane = tid & 63, wv = tid >> 6;
  float s = 0.f;
  for (int i = tid; i < N_GROUPS; i += 256) s += row_loss[i];
  s += __shfl_xor(s, 1);  s += __shfl_xor(s, 2);  s += __shfl_xor(s, 4);
  s += __shfl_xor(s, 8);  s += __shfl_xor(s, 16); s += __shfl_xor(s, 32);
  __shared__ float red[4];
  if (lane == 0) red[wv] = s;
  __syncthreads();
  if (tid == 0) out[0] = (red[0] + red[1] + red[2] + red[3]) * (1.0f / N_GROUPS);
}

extern "C" void kernel_launch(void* const* d_in, const int* in_sizes, int n_in,
                              void* d_out, int out_size, void* d_ws, size_t ws_size,
                              hipStream_t stream) {
  const float* emb = (const float*)d_in[0];
  const float* W = (const float*)d_in[1];
  const float* b = (const float*)d_in[2];
  const int* neg_perm = (const int*)d_in[4];
  float* out = (float*)d_out;

  ushort* wsu = (ushort*)d_ws;
  ushort* embB = wsu;                                       // 4,194,304 elems
  ushort* WB = wsu + (size_t)N_EMB * HID;                   // 196,608 elems
  ushort* predB = WB + (size_t)KDIM * HID;                  // 1,048,576 elems
  float* row_loss = (float*)(predB + (size_t)N_GROUPS * HID);

  const int n4 = N4_EMB + N4_W;
  to_bf16<<<(n4 + 255) / 256, 256, 0, stream>>>(emb, W, embB, WB);
  gemm_mfma<<<dim3(N_GROUPS / 64, HID / 16), 256, 0, stream>>>(embB, WB, b, predB);
  loss_rows<<<N_GROUPS, 256, 0, stream>>>(embB, predB, neg_perm, row_loss);
  reduce_mean<<<1, 256, 0, stream>>>(row_loss, out);
}

// Round 3
// 101.060 us; speedup vs baseline: 1.6467x; 1.2129x over previous
//
#include <hip/hip_runtime.h>

#define N_GROUPS 4096
#define K_POS 4
#define HID 256
#define M_NEG 256
#define KDIM 768  // (K_POS-1)*HID
#define N_EMB (N_GROUPS * K_POS)

typedef __attribute__((ext_vector_type(8))) short bf16x8;
typedef __attribute__((ext_vector_type(4))) float f32x4;
typedef __attribute__((ext_vector_type(4))) uint u32x4;

__device__ inline ushort f2bf(float f) {
  uint x = __float_as_uint(f);
  return (ushort)((x + 0x7fffu + ((x >> 16) & 1u)) >> 16);
}
__device__ inline float bf2f(ushort u) { return __uint_as_float(((uint)u) << 16); }

// dot of 8 bf16 (packed in u32x4) with 8 f32 p[0..7], accumulated into acc
__device__ inline void fma8(const u32x4 a, const float* __restrict__ p, float& acc) {
#pragma unroll
  for (int d = 0; d < 4; ++d) {
    const uint u = a[d];
    acc = fmaf(__uint_as_float(u << 16), p[2 * d], acc);
    acc = fmaf(__uint_as_float(u & 0xffff0000u), p[2 * d + 1], acc);
  }
}

// ---------------- Kernel 0: fp32 -> bf16 for emb and W ----------------
#define N4_EMB (N_EMB * HID / 4)
#define N4_W   (KDIM * HID / 4)
__global__ __launch_bounds__(256) void to_bf16(
    const float* __restrict__ emb, const float* __restrict__ W,
    ushort* __restrict__ embB, ushort* __restrict__ WB) {
  const int i = blockIdx.x * 256 + threadIdx.x;
  if (i < N4_EMB) {
    const float4 v = ((const float4*)emb)[i];
    ushort4 o = {f2bf(v.x), f2bf(v.y), f2bf(v.z), f2bf(v.w)};
    ((ushort4*)embB)[i] = o;
  } else if (i < N4_EMB + N4_W) {
    const int j = i - N4_EMB;
    const float4 v = ((const float4*)W)[j];
    ushort4 o = {f2bf(v.x), f2bf(v.y), f2bf(v.z), f2bf(v.w)};
    ((ushort4*)WB)[j] = o;
  }
}

// ---------------- Kernel 1: predicts = hist_x @ W^T + b (MFMA, f32 out) ----------------
// wave computes 16 rows x 64 cols; A fragment reused across 4 col-tiles.
__global__ __launch_bounds__(256) void gemm_mfma(
    const ushort* __restrict__ embB, const ushort* __restrict__ WB,
    const float* __restrict__ bias, float* __restrict__ pred) {
  const int wv = threadIdx.x >> 6, l = threadIdx.x & 63;
  const int mt = blockIdx.x * 4 + wv;   // 16-row tile, 0..255
  const int bn = blockIdx.y * 64;       // col base
  const int r = l & 15, g = l >> 4;

  const short* A = (const short*)embB + (size_t)(mt * 16 + r) * (K_POS * HID) + g * 8;
  f32x4 acc[4] = {{0,0,0,0},{0,0,0,0},{0,0,0,0},{0,0,0,0}};
  for (int k0 = 0; k0 < KDIM; k0 += 32) {
    const bf16x8 a = *(const bf16x8*)(A + k0);
#pragma unroll
    for (int j = 0; j < 4; ++j) {
      const bf16x8 b = *(const bf16x8*)((const short*)WB + (size_t)(bn + j * 16 + r) * KDIM + g * 8 + k0);
      acc[j] = __builtin_amdgcn_mfma_f32_16x16x32_bf16(a, b, acc[j], 0, 0, 0);
    }
  }
  // C/D: col = lane&15, row = (lane>>4)*4 + i
#pragma unroll
  for (int j = 0; j < 4; ++j) {
    const int col = bn + j * 16 + r;
    const float bb = bias[col];
#pragma unroll
    for (int i = 0; i < 4; ++i)
      pred[(size_t)(mt * 16 + g * 4 + i) * HID + col] = acc[j][i] + bb;
  }
}

// ---------------- Kernel 2: per-row loss; lane owns 4 negatives (no shuffles in loop) ----
__global__ __launch_bounds__(256) void loss_rows(
    const ushort* __restrict__ embB, const float* __restrict__ pred,
    const int* __restrict__ neg_perm, float* __restrict__ row_loss) {
  const int n4 = blockIdx.x * 4;
  const int tid = threadIdx.x;
  const int lane = tid & 63, wv = tid >> 6;
  const int n = n4 + wv;  // wave wv owns row n
  __shared__ float predS[4 * HID];

  // cooperative stage: 4 rows of f32 pred (4KB), coalesced float4
  ((float4*)predS)[tid] = ((const float4*)(pred + (size_t)n4 * HID))[tid];
  __syncthreads();
  const float* wp = predS + wv * HID;

  // positive logit (one butterfly, one-time)
  float posv;
  {
    const u32x4 h = *(const u32x4*)(embB + ((size_t)n * K_POS + K_POS - 1) * HID + lane * 8);
    float s = 0.f;
    fma8(h, wp + lane * 8, s);
    s += __shfl_xor(s, 1);  s += __shfl_xor(s, 2);  s += __shfl_xor(s, 4);
    s += __shfl_xor(s, 8);  s += __shfl_xor(s, 16); s += __shfl_xor(s, 32);
    posv = s;
  }

  // lane owns negatives 4*lane .. 4*lane+3 of row n
  const int4 raw = *(const int4*)(neg_perm + (size_t)n * M_NEG + lane * 4);
  const int base = n * K_POS;
  const ushort* rp0 = embB + (size_t)(raw.x + (raw.x >= base ? K_POS : 0)) * HID;
  const ushort* rp1 = embB + (size_t)(raw.y + (raw.y >= base ? K_POS : 0)) * HID;
  const ushort* rp2 = embB + (size_t)(raw.z + (raw.z >= base ? K_POS : 0)) * HID;
  const ushort* rp3 = embB + (size_t)(raw.w + (raw.w >= base ? K_POS : 0)) * HID;

  float ac0 = 0.f, ac1 = 0.f, ac2 = 0.f, ac3 = 0.f;
#pragma unroll 1
  for (int c = 0; c < HID; c += 32) {
    u32x4 a0[4], a1[4], a2[4], a3[4];
#pragma unroll
    for (int q = 0; q < 4; ++q) {
      a0[q] = *(const u32x4*)(rp0 + c + 8 * q);
      a1[q] = *(const u32x4*)(rp1 + c + 8 * q);
      a2[q] = *(const u32x4*)(rp2 + c + 8 * q);
      a3[q] = *(const u32x4*)(rp3 + c + 8 * q);
    }
    float p[32];
#pragma unroll
    for (int j = 0; j < 8; ++j) {
      const float4 v = *(const float4*)&wp[c + 4 * j];  // uniform -> LDS broadcast
      p[4 * j + 0] = v.x; p[4 * j + 1] = v.y; p[4 * j + 2] = v.z; p[4 * j + 3] = v.w;
    }
#pragma unroll
    for (int q = 0; q < 4; ++q) {
      fma8(a0[q], p + 8 * q, ac0);
      fma8(a1[q], p + 8 * q, ac1);
      fma8(a2[q], p + 8 * q, ac2);
      fma8(a3[q], p + 8 * q, ac3);
    }
  }

  // wave-level logsumexp (single butterfly pair per row)
  float mx = fmaxf(fmaxf(ac0, ac1), fmaxf(ac2, ac3));
  mx = fmaxf(mx, __shfl_xor(mx, 1));  mx = fmaxf(mx, __shfl_xor(mx, 2));
  mx = fmaxf(mx, __shfl_xor(mx, 4));  mx = fmaxf(mx, __shfl_xor(mx, 8));
  mx = fmaxf(mx, __shfl_xor(mx, 16)); mx = fmaxf(mx, __shfl_xor(mx, 32));
  const float gmx = fmaxf(mx, posv);

  float se = __expf(ac0 - gmx) + __expf(ac1 - gmx) + __expf(ac2 - gmx) + __expf(ac3 - gmx);
  se += __shfl_xor(se, 1);  se += __shfl_xor(se, 2);  se += __shfl_xor(se, 4);
  se += __shfl_xor(se, 8);  se += __shfl_xor(se, 16); se += __shfl_xor(se, 32);

  if (lane == 0) row_loss[n] = __logf(se + __expf(posv - gmx)) + gmx - posv;
}

// ---------------- Kernel 3: deterministic mean ----------------
__global__ __launch_bounds__(256) void reduce_mean(
    const float* __restrict__ row_loss, float* __restrict__ out) {
  const int tid = threadIdx.x;
  const int lane = tid & 63, wv = tid >> 6;
  float s = 0.f;
  for (int i = tid; i < N_GROUPS; i += 256) s += row_loss[i];
  s += __shfl_xor(s, 1);  s += __shfl_xor(s, 2);  s += __shfl_xor(s, 4);
  s += __shfl_xor(s, 8);  s += __shfl_xor(s, 16); s += __shfl_xor(s, 32);
  __shared__ float red[4];
  if (lane == 0) red[wv] = s;
  __syncthreads();
  if (tid == 0) out[0] = (red[0] + red[1] + red[2] + red[3]) * (1.0f / N_GROUPS);
}

extern "C" void kernel_launch(void* const* d_in, const int* in_sizes, int n_in,
                              void* d_out, int out_size, void* d_ws, size_t ws_size,
                              hipStream_t stream) {
  const float* emb = (const float*)d_in[0];
  const float* W = (const float*)d_in[1];
  const float* b = (const float*)d_in[2];
  const int* neg_perm = (const int*)d_in[4];
  float* out = (float*)d_out;

  ushort* embB = (ushort*)d_ws;                              // 8 MB
  ushort* WB = embB + (size_t)N_EMB * HID;                   // 0.4 MB
  float* pred = (float*)(WB + (size_t)KDIM * HID);           // 4 MB (f32)
  float* row_loss = pred + (size_t)N_GROUPS * HID;           // 16 KB

  const int n4 = N4_EMB + N4_W;
  to_bf16<<<(n4 + 255) / 256, 256, 0, stream>>>(emb, W, embB, WB);
  gemm_mfma<<<dim3(N_GROUPS / 64, HID / 64), 256, 0, stream>>>(embB, WB, b, pred);
  loss_rows<<<N_GROUPS / 4, 256, 0, stream>>>(embB, pred, neg_perm, row_loss);
  reduce_mean<<<1, 256, 0, stream>>>(row_loss, out);
}